// Round 5
// baseline (267.162 us; speedup 1.0000x reference)
//
#include <hip/hip_runtime.h>
#include <hip/hip_bf16.h>

#define C   64
#define Hh  128
#define Ww  128
#define HW  16384

typedef __attribute__((ext_vector_type(8))) short bf16x8;
typedef __attribute__((ext_vector_type(4))) float f32x4;

__device__ __forceinline__ unsigned short f2bf(float f) {
    unsigned u = __builtin_bit_cast(unsigned, f);
    unsigned r = (u + 0x7fff + ((u >> 16) & 1)) >> 16;
    return (unsigned short)r;
}

// ---------------------------------------------------------------------------
// Proj: y[img][pix][co] = bf16(relu( sum_ci x[img][ci][pix]*pw[co][ci] + sh ))
// MFMA 16x16x32, M=pix(256), N=co(64), K=64. One launch for u(y<8) + v(>=8).
// Staging: float4 loads, wave = 1024 contiguous bytes per instruction.
// BN-folded proj weights computed per-block in LDS (prep kernel eliminated).
// Tail: y==0/1 block slices repack conv weights to wp[ch][tap][co][ci32].
// ---------------------------------------------------------------------------
__global__ __launch_bounds__(256, 3) void proj_mfma(
    const float* __restrict__ xu, const float* __restrict__ xv,
    const float* __restrict__ pu_w, const float* __restrict__ pu_g,
    const float* __restrict__ pu_b, const float* __restrict__ pu_m,
    const float* __restrict__ pu_v,
    const float* __restrict__ pv_w, const float* __restrict__ pv_g,
    const float* __restrict__ pv_b, const float* __restrict__ pv_m,
    const float* __restrict__ pv_v,
    const float* __restrict__ conv_w,
    short* __restrict__ wpu, short* __restrict__ wpv,
    short* __restrict__ yu, short* __restrict__ yv)
{
    __shared__ short xs[256 * 72];      // [pix][64ci + 8 pad] bf16 36,864 B
    __shared__ short pwl[64 * 72];      // [co][64ci + 8 pad]         9,216 B
    __shared__ float ssh[64];

    const int img16 = blockIdx.y;
    const int sel   = img16 >> 3;
    const int img   = img16 & 7;
    const float* x  = sel ? xv   : xu;
    const float* pw = sel ? pv_w : pu_w;
    const float* pg = sel ? pv_g : pu_g;
    const float* pb = sel ? pv_b : pu_b;
    const float* pm = sel ? pv_m : pu_m;
    const float* pv = sel ? pv_v : pu_v;
    short* y        = sel ? yv   : yu;

    const int pix0 = blockIdx.x * 256;
    const int tid  = threadIdx.x;

    // ---- fold BN scale into proj weights, in LDS (2048 ci-pairs) ----
    for (int e = tid; e < 2048; e += 256) {
        const int co = e >> 5;
        const int ci0 = (e & 31) * 2;
        const float scale = pg[co] * rsqrtf(pv[co] + 1e-5f);
        const int packed = (int)f2bf(pw[co * 64 + ci0] * scale)
                         | ((int)f2bf(pw[co * 64 + ci0 + 1] * scale) << 16);
        *(int*)&pwl[co * 72 + ci0] = packed;
    }
    if (tid < 64) {
        const float scale = pg[tid] * rsqrtf(pv[tid] + 1e-5f);
        ssh[tid] = pb[tid] - pm[tid] * scale;
    }

    // ---- stage x: [ci][pix] fp32 -> [pix][ci] bf16, float4 bursts ----
    const float* xb = x + (size_t)img * C * HW;
    const int qd = tid & 63;          // pixel quad
    const int cp = tid >> 6;          // ci-pair group
#pragma unroll
    for (int k = 0; k < 8; ++k) {
        const int pairIdx = cp * 8 + k;
        const int ci0 = pairIdx * 2;
        const f32x4 a = *(const f32x4*)&xb[(size_t)ci0 * HW + pix0 + qd * 4];
        const f32x4 b = *(const f32x4*)&xb[(size_t)(ci0 + 1) * HW + pix0 + qd * 4];
#pragma unroll
        for (int j = 0; j < 4; ++j) {
            const int packed = (int)f2bf(a[j]) | ((int)f2bf(b[j]) << 16);
            *(int*)&xs[(qd * 4 + j) * 72 + ci0] = packed;
        }
    }
    __syncthreads();

    const int wq = tid >> 6;
    const int lane = tid & 63;
    const int lx = lane & 15;
    const int q  = lane >> 4;

    f32x4 acc[4][4];
#pragma unroll
    for (int mt = 0; mt < 4; ++mt)
#pragma unroll
        for (int nt = 0; nt < 4; ++nt) acc[mt][nt] = (f32x4){0.f, 0.f, 0.f, 0.f};

#pragma unroll
    for (int kc = 0; kc < 2; ++kc) {
        bf16x8 a[4], b[4];
#pragma unroll
        for (int mt = 0; mt < 4; ++mt)
            a[mt] = *(const bf16x8*)&xs[((wq * 4 + mt) * 16 + lx) * 72 + kc * 32 + q * 8];
#pragma unroll
        for (int nt = 0; nt < 4; ++nt)
            b[nt] = *(const bf16x8*)&pwl[(nt * 16 + lx) * 72 + kc * 32 + q * 8];
#pragma unroll
        for (int mt = 0; mt < 4; ++mt)
#pragma unroll
            for (int nt = 0; nt < 4; ++nt)
                acc[mt][nt] = __builtin_amdgcn_mfma_f32_16x16x32_bf16(a[mt], b[nt], acc[mt][nt], 0, 0, 0);
    }

    // ---- epilogue: relu+shift -> bf16 back into xs as [pix][co], then
    //      coalesced int4 copy-out ----
    __syncthreads();      // all LDS reads for MFMA done
#pragma unroll
    for (int mt = 0; mt < 4; ++mt)
#pragma unroll
        for (int nt = 0; nt < 4; ++nt)
#pragma unroll
            for (int r = 0; r < 4; ++r) {
                const int px = (wq * 4 + mt) * 16 + q * 4 + r;
                const int co = nt * 16 + lx;
                float vv = acc[mt][nt][r] + ssh[co];
                vv = fmaxf(vv, 0.f);
                xs[px * 72 + co] = (short)f2bf(vv);
            }
    __syncthreads();
    short* yo = y + ((size_t)img * HW + pix0) * C;
#pragma unroll
    for (int it = 0; it < 8; ++it) {
        const int idx = tid + it * 256;      // 2048 int4 chunks
        const int oct = idx & 7, px = idx >> 3;
        *(int4*)&yo[(size_t)px * C + oct * 8] = *(const int4*)&xs[px * 72 + oct * 8];
    }

    // ---- tail: conv-weight repack on y-slices 0 (u) and 1 (v) ----
    if (img16 < 2) {
        short* wpx = img16 ? wpv : wpu;
        const int c = img16;
        for (int idx = blockIdx.x * 256 + tid; idx < 36864; idx += 64 * 256) {
            const int ci = idx & 31;
            const int co = (idx >> 5) & 63;
            const int r3 = idx >> 11;          // ch*9 + tap
            const int tap = r3 % 9;
            const int ch  = r3 / 9;
            const float src = conv_w[(size_t)(co * 128 + c * 64 + ch * 32 + ci) * 9 + tap];
            wpx[idx] = (short)f2bf(src);
        }
    }
}

// ---------------------------------------------------------------------------
// Conv 3x3 pad=1, implicit GEMM MFMA 16x16x32. Tile 4h x 32w (1024 blocks).
// M=co(64), N=128 px; wave wq owns h-row wq (2 nt tiles of 16 w).
// Activations (both ci-halves) staged ONCE: [6h x 34w][64+4pad] = 27.7 KB,
// single barrier. Weight A-fragments read directly from L2 (wp is 73 KB,
// L2-resident; 16 B/lane coalesced) -> straight 144-MFMA run per wave.
// Epilogue transposes each 16co x 128px acc slab through LDS so all HBM
// reads/writes are full-line coalesced float4.
// FUSED=false: write ou[img][co][hw] fp32 (stays LLC-resident).
// FUSED=true : out[b][sx][sy] = acc + bias + ou[b*4+sx], nontemporal.
// LDS 36.5 KB -> 4 blocks/CU (16 waves/CU).
// ---------------------------------------------------------------------------
template<bool FUSED>
__global__ __launch_bounds__(256, 4) void conv_fused(
    const short* __restrict__ act, const short* __restrict__ wp,
    const float* __restrict__ oug, const float* __restrict__ bias,
    float* __restrict__ outp)
{
    __shared__ short xs[204 * 68];     // 27,744 B halo [cell][ci]
    __shared__ float ts[16 * 132];     //  8,448 B transpose slab
    __shared__ float sbias[64];

    const int img = blockIdx.y;
    const int tx = blockIdx.x & 3, ty = blockIdx.x >> 2;
    const int h0 = ty * 4, w0 = tx * 32;
    const int tid = threadIdx.x;
    const int wq = tid >> 6;
    const int lane = tid & 63;
    const int lx = lane & 15;
    const int q  = lane >> 4;
    const int q8 = q * 8;

    if (FUSED && tid < 64) sbias[tid] = bias[tid];

    // ---- stage halo (both ci halves), zero OOB ----
    const short* ub = act + (size_t)img * HW * C;
    for (int idx = tid; idx < 1632; idx += 256) {   // 204 cells x 8 octs
        const int oct = idx & 7;
        const int cell = idx >> 3;
        const int h = cell / 34, w = cell - h * 34;
        const int gh = h0 - 1 + h, gw = w0 - 1 + w;
        int4 v = {0, 0, 0, 0};
        if (gh >= 0 && gh < Hh && gw >= 0 && gw < Ww)
            v = *(const int4*)&ub[(size_t)(gh * Ww + gw) * C + oct * 8];
        *(int4*)(&xs[cell * 68 + oct * 8]) = v;
    }
    __syncthreads();

    f32x4 acc[4][2];
#pragma unroll
    for (int mt = 0; mt < 4; ++mt)
#pragma unroll
        for (int nt = 0; nt < 2; ++nt) acc[mt][nt] = (f32x4){0.f, 0.f, 0.f, 0.f};

    // ---- 144 MFMAs, weights direct from L2, no barriers ----
#pragma unroll
    for (int ch = 0; ch < 2; ++ch)
#pragma unroll
        for (int t = 0; t < 9; ++t) {
            const int ky = t / 3;
            const int kx = t - ky * 3;
            bf16x8 a[4], b[2];
#pragma unroll
            for (int mt = 0; mt < 4; ++mt)
                a[mt] = *(const bf16x8*)&wp[(((ch * 9 + t) * 64) + mt * 16 + lx) * 32 + q8];
#pragma unroll
            for (int nt = 0; nt < 2; ++nt) {
                const int cell = (wq + ky) * 34 + nt * 16 + lx + kx;
                b[nt] = *(const bf16x8*)&xs[cell * 68 + ch * 32 + q8];
            }
#pragma unroll
            for (int mt = 0; mt < 4; ++mt)
#pragma unroll
                for (int nt = 0; nt < 2; ++nt)
                    acc[mt][nt] = __builtin_amdgcn_mfma_f32_16x16x32_bf16(a[mt], b[nt], acc[mt][nt], 0, 0, 0);
        }

    // ---- epilogue: per-mt LDS transpose -> full-line coalesced I/O ----
    if (FUSED) {
#pragma unroll
        for (int mt = 0; mt < 4; ++mt)
#pragma unroll
            for (int nt = 0; nt < 2; ++nt)
#pragma unroll
                for (int r = 0; r < 4; ++r)
                    acc[mt][nt][r] += sbias[mt * 16 + q * 4 + r];
    }

    const int b  = img >> 2;
    const int sy = img & 3;

#pragma unroll
    for (int mt = 0; mt < 4; ++mt) {
        __syncthreads();
#pragma unroll
        for (int nt = 0; nt < 2; ++nt)
#pragma unroll
            for (int r = 0; r < 4; ++r)
                ts[(q * 4 + r) * 132 + wq * 32 + nt * 16 + lx] = acc[mt][nt][r];
        __syncthreads();
        if (!FUSED) {
            float* ob = outp + (size_t)img * C * HW;
#pragma unroll
            for (int k = 0; k < 2; ++k) {
                const int f = tid + k * 256;        // 512 float4 chunks
                const int co = f >> 5, c2 = f & 31;
                const int px = c2 * 4;
                const int h2 = px >> 5, w2 = px & 31;
                *(f32x4*)&ob[(size_t)(mt * 16 + co) * HW + (h0 + h2) * Ww + w0 + w2] =
                    *(const f32x4*)&ts[co * 132 + c2 * 4];
            }
        } else {
#pragma unroll
            for (int k = 0; k < 2; ++k) {
                const int f = tid + k * 256;
                const int co = f >> 5, c2 = f & 31;
                const int px = c2 * 4;
                const int h2 = px >> 5, w2 = px & 31;
                const size_t off = (size_t)(mt * 16 + co) * HW + (h0 + h2) * Ww + w0 + w2;
                const f32x4 tv = *(const f32x4*)&ts[co * 132 + c2 * 4];
#pragma unroll
                for (int sx = 0; sx < 4; ++sx) {
                    const f32x4 o = *(const f32x4*)&oug[(size_t)(b * 4 + sx) * C * HW + off];
                    f32x4 rr = tv + o;
                    __builtin_nontemporal_store(rr,
                        (f32x4*)&outp[((size_t)((b * 4 + sx) * 4 + sy)) * C * HW + off]);
                }
            }
        }
    }
}

// ---------------------------------------------------------------------------
extern "C" void kernel_launch(void* const* d_in, const int* in_sizes, int n_in,
                              void* d_out, int out_size, void* d_ws, size_t ws_size,
                              hipStream_t stream)
{
    const float* u        = (const float*)d_in[0];
    const float* v        = (const float*)d_in[1];
    const float* pu_w     = (const float*)d_in[2];
    const float* pu_gamma = (const float*)d_in[3];
    const float* pu_beta  = (const float*)d_in[4];
    const float* pu_mean  = (const float*)d_in[5];
    const float* pu_var   = (const float*)d_in[6];
    const float* pv_w     = (const float*)d_in[7];
    const float* pv_gamma = (const float*)d_in[8];
    const float* pv_beta  = (const float*)d_in[9];
    const float* pv_mean  = (const float*)d_in[10];
    const float* pv_var   = (const float*)d_in[11];
    const float* conv_w   = (const float*)d_in[12];
    const float* conv_b   = (const float*)d_in[13];
    float* out = (float*)d_out;

    char* ws = (char*)d_ws;
    short* uf  = (short*)(ws);                         // 16,777,216 B
    short* vf  = (short*)(ws + 16777216);              // 16,777,216 B
    float* ou  = (float*)(ws + 33554432);              // 33,554,432 B
    char*  aux = ws + 67108864;
    short* wpu = (short*)(aux);                        // 73,728 B
    short* wpv = (short*)(aux + 73728);                // 73,728 B

    dim3 gp(64, 16);
    proj_mfma<<<gp, 256, 0, stream>>>(u, v,
                                      pu_w, pu_gamma, pu_beta, pu_mean, pu_var,
                                      pv_w, pv_gamma, pv_beta, pv_mean, pv_var,
                                      conv_w, wpu, wpv, uf, vf);

    dim3 gc(128, 8);
    conv_fused<false><<<gc, 256, 0, stream>>>(uf, wpu, nullptr, nullptr, ou);
    conv_fused<true ><<<gc, 256, 0, stream>>>(vf, wpv, ou, conv_b, out);
}

// Round 6
// 258.930 us; speedup vs baseline: 1.0318x; 1.0318x over previous
//
#include <hip/hip_runtime.h>
#include <hip/hip_bf16.h>

#define C   64
#define Hh  128
#define Ww  128
#define HW  16384

typedef __attribute__((ext_vector_type(8))) short bf16x8;
typedef __attribute__((ext_vector_type(4))) float f32x4;

__device__ __forceinline__ unsigned short f2bf(float f) {
    unsigned u = __builtin_bit_cast(unsigned, f);
    unsigned r = (u + 0x7fff + ((u >> 16) & 1)) >> 16;
    return (unsigned short)r;
}

// ---------------------------------------------------------------------------
// Proj: y[img][pix][co] = bf16(relu( sum_ci x[img][ci][pix]*pw[co][ci] + sh ))
// MFMA 16x16x32, M=pix(256), N=co(64), K=64. One launch for u(y<8) + v(>=8).
// xs layout: [pix][64ci] pitch 64 (no pad) with 16-B-chunk XOR swizzle
// (chunk ^= px&7): staging int4 writes hit all 32 banks; MFMA A-reads 2-way.
// BN fold + conv-weight repack fused in (no prep kernel).
// ---------------------------------------------------------------------------
__global__ __launch_bounds__(256, 3) void proj_mfma(
    const float* __restrict__ xu, const float* __restrict__ xv,
    const float* __restrict__ pu_w, const float* __restrict__ pu_g,
    const float* __restrict__ pu_b, const float* __restrict__ pu_m,
    const float* __restrict__ pu_v,
    const float* __restrict__ pv_w, const float* __restrict__ pv_g,
    const float* __restrict__ pv_b, const float* __restrict__ pv_m,
    const float* __restrict__ pv_v,
    const float* __restrict__ conv_w,
    short* __restrict__ wpu, short* __restrict__ wpv,
    short* __restrict__ yu, short* __restrict__ yv)
{
    __shared__ short xs[256 * 64];      // [pix][64ci] swizzled, 32,768 B
    __shared__ short pwl[64 * 72];      // [co][64ci + 8 pad]      9,216 B
    __shared__ float ssh[64];

    const int img16 = blockIdx.y;
    const int sel   = img16 >> 3;
    const int img   = img16 & 7;
    const float* x  = sel ? xv   : xu;
    const float* pw = sel ? pv_w : pu_w;
    const float* pg = sel ? pv_g : pu_g;
    const float* pb = sel ? pv_b : pu_b;
    const float* pm = sel ? pv_m : pu_m;
    const float* pv = sel ? pv_v : pu_v;
    short* y        = sel ? yv   : yu;

    const int pix0 = blockIdx.x * 256;
    const int tid  = threadIdx.x;

    // ---- fold BN scale into proj weights, in LDS ----
    for (int e = tid; e < 2048; e += 256) {
        const int co = e >> 5;
        const int ci0 = (e & 31) * 2;
        const float scale = pg[co] * rsqrtf(pv[co] + 1e-5f);
        const int packed = (int)f2bf(pw[co * 64 + ci0] * scale)
                         | ((int)f2bf(pw[co * 64 + ci0 + 1] * scale) << 16);
        *(int*)&pwl[co * 72 + ci0] = packed;
    }
    if (tid < 64) {
        const float scale = pg[tid] * rsqrtf(pv[tid] + 1e-5f);
        ssh[tid] = pb[tid] - pm[tid] * scale;
    }

    // ---- stage x: [ci][pix] fp32 -> [pix][ci] bf16; float4 global reads,
    //      register-packed int4 LDS writes at swizzled chunk ----
    const float* xb = x + (size_t)img * C * HW;
    const int qd = tid & 63;          // pixel quad
    const int cp = tid >> 6;          // 16-ci group
#pragma unroll
    for (int kk = 0; kk < 2; ++kk) {
        int4 pk[4];
#pragma unroll
        for (int k4 = 0; k4 < 4; ++k4) {
            const int ci0 = (cp * 8 + kk * 4 + k4) * 2;
            const f32x4 a = *(const f32x4*)&xb[(size_t)ci0 * HW + pix0 + qd * 4];
            const f32x4 b = *(const f32x4*)&xb[(size_t)(ci0 + 1) * HW + pix0 + qd * 4];
#pragma unroll
            for (int j = 0; j < 4; ++j) {
                const int packed = (int)f2bf(a[j]) | ((int)f2bf(b[j]) << 16);
                if (k4 == 0) pk[j].x = packed;
                else if (k4 == 1) pk[j].y = packed;
                else if (k4 == 2) pk[j].z = packed;
                else pk[j].w = packed;
            }
        }
        const int chunk = cp * 2 + kk;
#pragma unroll
        for (int j = 0; j < 4; ++j) {
            const int px = qd * 4 + j;
            *(int4*)&xs[px * 64 + ((chunk ^ (px & 7)) << 3)] = pk[j];
        }
    }
    __syncthreads();

    const int wq = tid >> 6;
    const int lane = tid & 63;
    const int lx = lane & 15;
    const int q  = lane >> 4;

    f32x4 acc[4][4];
#pragma unroll
    for (int mt = 0; mt < 4; ++mt)
#pragma unroll
        for (int nt = 0; nt < 4; ++nt) acc[mt][nt] = (f32x4){0.f, 0.f, 0.f, 0.f};

#pragma unroll
    for (int kc = 0; kc < 2; ++kc) {
        bf16x8 a[4], b[4];
#pragma unroll
        for (int mt = 0; mt < 4; ++mt) {
            const int px = (wq * 4 + mt) * 16 + lx;
            a[mt] = *(const bf16x8*)&xs[px * 64 + (((kc * 4 + q) ^ (lx & 7)) << 3)];
        }
#pragma unroll
        for (int nt = 0; nt < 4; ++nt)
            b[nt] = *(const bf16x8*)&pwl[(nt * 16 + lx) * 72 + kc * 32 + q * 8];
#pragma unroll
        for (int mt = 0; mt < 4; ++mt)
#pragma unroll
            for (int nt = 0; nt < 4; ++nt)
                acc[mt][nt] = __builtin_amdgcn_mfma_f32_16x16x32_bf16(a[mt], b[nt], acc[mt][nt], 0, 0, 0);
    }

    // ---- epilogue: relu+shift -> bf16 into xs as [pix][co] (same swizzle),
    //      then coalesced int4 copy-out ----
    __syncthreads();
#pragma unroll
    for (int mt = 0; mt < 4; ++mt)
#pragma unroll
        for (int nt = 0; nt < 4; ++nt)
#pragma unroll
            for (int r = 0; r < 4; ++r) {
                const int px = (wq * 4 + mt) * 16 + q * 4 + r;
                const int co = nt * 16 + lx;
                float vv = acc[mt][nt][r] + ssh[co];
                vv = fmaxf(vv, 0.f);
                xs[px * 64 + (co ^ ((px & 7) << 3))] = (short)f2bf(vv);
            }
    __syncthreads();
    short* yo = y + ((size_t)img * HW + pix0) * C;
#pragma unroll
    for (int it = 0; it < 8; ++it) {
        const int idx = tid + it * 256;      // 2048 int4 chunks
        const int oct = idx & 7, px = idx >> 3;
        *(int4*)&yo[(size_t)px * C + oct * 8] =
            *(const int4*)&xs[px * 64 + ((oct ^ (px & 7)) << 3)];
    }

    // ---- tail: conv-weight repack on y-slices 0 (u) and 1 (v) ----
    if (img16 < 2) {
        short* wpx = img16 ? wpv : wpu;
        const int c = img16;
        for (int idx = blockIdx.x * 256 + tid; idx < 36864; idx += 64 * 256) {
            const int ci = idx & 31;
            const int co = (idx >> 5) & 63;
            const int r3 = idx >> 11;          // ch*9 + tap
            const int tap = r3 % 9;
            const int ch  = r3 / 9;
            const float src = conv_w[(size_t)(co * 128 + c * 64 + ch * 32 + ci) * 9 + tap];
            wpx[idx] = (short)f2bf(src);
        }
    }
}

// ---------------------------------------------------------------------------
// Conv 3x3 pad=1, implicit GEMM MFMA 16x16x32. Tile 4h x 32w, 128-thread
// blocks (2 waves), 4 blocks/CU. Each wave computes 64co x 64px (2h x 32w):
// per-wave L2 weight traffic is HALVED vs 32px waves (A reused over 4 nt).
// Halo [6h x 34w][64ci] pitch 72 (16-B aligned rows, 2-way-read banks).
// Weight A-fragments read directly from L2 (73 KB resident, 16 B/lane).
// Epilogue transposes each 16co x 128px slab through LDS -> full-line I/O.
// FUSED=false: write ou[img][co][hw] fp32 (stays LLC-resident).
// FUSED=true : out[b][sx][sy] = acc + bias + ou[b*4+sx], nontemporal.
// LDS 38.1 KB -> 4 blocks/CU (8 waves/CU).
// ---------------------------------------------------------------------------
template<bool FUSED>
__global__ __launch_bounds__(128, 2) void conv_fused(
    const short* __restrict__ act, const short* __restrict__ wp,
    const float* __restrict__ oug, const float* __restrict__ bias,
    float* __restrict__ outp)
{
    __shared__ short xs[204 * 72];     // 29,376 B halo [cell][ci]
    __shared__ float ts[16 * 132];     //  8,448 B transpose slab
    __shared__ float sbias[64];

    const int img = blockIdx.y;
    const int tx = blockIdx.x & 3, ty = blockIdx.x >> 2;
    const int h0 = ty * 4, w0 = tx * 32;
    const int tid = threadIdx.x;
    const int wq = tid >> 6;           // 0..1: wave's 2 h-rows
    const int lane = tid & 63;
    const int lx = lane & 15;
    const int q  = lane >> 4;
    const int q8 = q * 8;

    if (FUSED && tid < 64) sbias[tid] = bias[tid];

    // ---- stage halo (both ci halves), zero OOB ----
    const short* ub = act + (size_t)img * HW * C;
    for (int idx = tid; idx < 1632; idx += 128) {   // 204 cells x 8 octs
        const int oct = idx & 7;
        const int cell = idx >> 3;
        const int h = cell / 34, w = cell - h * 34;
        const int gh = h0 - 1 + h, gw = w0 - 1 + w;
        int4 v = {0, 0, 0, 0};
        if (gh >= 0 && gh < Hh && gw >= 0 && gw < Ww)
            v = *(const int4*)&ub[(size_t)(gh * Ww + gw) * C + oct * 8];
        *(int4*)(&xs[cell * 72 + oct * 8]) = v;
    }
    __syncthreads();

    f32x4 acc[4][4];
#pragma unroll
    for (int mt = 0; mt < 4; ++mt)
#pragma unroll
        for (int nt = 0; nt < 4; ++nt) acc[mt][nt] = (f32x4){0.f, 0.f, 0.f, 0.f};

    // ---- 288 MFMAs/wave, weights direct from L2, no barriers ----
#pragma unroll
    for (int ch = 0; ch < 2; ++ch)
#pragma unroll
        for (int t = 0; t < 9; ++t) {
            const int ky = t / 3;
            const int kx = t - ky * 3;
            bf16x8 a[4], b[4];
#pragma unroll
            for (int mt = 0; mt < 4; ++mt)
                a[mt] = *(const bf16x8*)&wp[(((ch * 9 + t) * 64) + mt * 16 + lx) * 32 + q8];
#pragma unroll
            for (int nt = 0; nt < 4; ++nt) {
                const int cell = (2 * wq + (nt >> 1) + ky) * 34 + (nt & 1) * 16 + lx + kx;
                b[nt] = *(const bf16x8*)&xs[cell * 72 + ch * 32 + q8];
            }
#pragma unroll
            for (int mt = 0; mt < 4; ++mt)
#pragma unroll
                for (int nt = 0; nt < 4; ++nt)
                    acc[mt][nt] = __builtin_amdgcn_mfma_f32_16x16x32_bf16(a[mt], b[nt], acc[mt][nt], 0, 0, 0);
        }

    // ---- epilogue: per-mt LDS transpose -> full-line coalesced I/O ----
    if (FUSED) {
#pragma unroll
        for (int mt = 0; mt < 4; ++mt)
#pragma unroll
            for (int nt = 0; nt < 4; ++nt)
#pragma unroll
                for (int r = 0; r < 4; ++r)
                    acc[mt][nt][r] += sbias[mt * 16 + q * 4 + r];
    }

    const int b  = img >> 2;
    const int sy = img & 3;

#pragma unroll
    for (int mt = 0; mt < 4; ++mt) {
        __syncthreads();
#pragma unroll
        for (int nt = 0; nt < 4; ++nt)
#pragma unroll
            for (int r = 0; r < 4; ++r)
                ts[(q * 4 + r) * 132 + (2 * wq + (nt >> 1)) * 32 + (nt & 1) * 16 + lx]
                    = acc[mt][nt][r];
        __syncthreads();
        if (!FUSED) {
            float* ob = outp + (size_t)img * C * HW;
#pragma unroll
            for (int k = 0; k < 4; ++k) {
                const int f = tid + k * 128;        // 512 float4 chunks
                const int co = f >> 5, c2 = f & 31;
                const int px = c2 * 4;
                const int h2 = px >> 5, w2 = px & 31;
                *(f32x4*)&ob[(size_t)(mt * 16 + co) * HW + (h0 + h2) * Ww + w0 + w2] =
                    *(const f32x4*)&ts[co * 132 + c2 * 4];
            }
        } else {
#pragma unroll
            for (int k = 0; k < 4; ++k) {
                const int f = tid + k * 128;
                const int co = f >> 5, c2 = f & 31;
                const int px = c2 * 4;
                const int h2 = px >> 5, w2 = px & 31;
                const size_t off = (size_t)(mt * 16 + co) * HW + (h0 + h2) * Ww + w0 + w2;
                const f32x4 tv = *(const f32x4*)&ts[co * 132 + c2 * 4];
#pragma unroll
                for (int sx = 0; sx < 4; ++sx) {
                    const f32x4 o = *(const f32x4*)&oug[(size_t)(b * 4 + sx) * C * HW + off];
                    f32x4 rr = tv + o;
                    __builtin_nontemporal_store(rr,
                        (f32x4*)&outp[((size_t)((b * 4 + sx) * 4 + sy)) * C * HW + off]);
                }
            }
        }
    }
}

// ---------------------------------------------------------------------------
extern "C" void kernel_launch(void* const* d_in, const int* in_sizes, int n_in,
                              void* d_out, int out_size, void* d_ws, size_t ws_size,
                              hipStream_t stream)
{
    const float* u        = (const float*)d_in[0];
    const float* v        = (const float*)d_in[1];
    const float* pu_w     = (const float*)d_in[2];
    const float* pu_gamma = (const float*)d_in[3];
    const float* pu_beta  = (const float*)d_in[4];
    const float* pu_mean  = (const float*)d_in[5];
    const float* pu_var   = (const float*)d_in[6];
    const float* pv_w     = (const float*)d_in[7];
    const float* pv_gamma = (const float*)d_in[8];
    const float* pv_beta  = (const float*)d_in[9];
    const float* pv_mean  = (const float*)d_in[10];
    const float* pv_var   = (const float*)d_in[11];
    const float* conv_w   = (const float*)d_in[12];
    const float* conv_b   = (const float*)d_in[13];
    float* out = (float*)d_out;

    char* ws = (char*)d_ws;
    short* uf  = (short*)(ws);                         // 16,777,216 B
    short* vf  = (short*)(ws + 16777216);              // 16,777,216 B
    float* ou  = (float*)(ws + 33554432);              // 33,554,432 B
    char*  aux = ws + 67108864;
    short* wpu = (short*)(aux);                        // 73,728 B
    short* wpv = (short*)(aux + 73728);                // 73,728 B

    dim3 gp(64, 16);
    proj_mfma<<<gp, 256, 0, stream>>>(u, v,
                                      pu_w, pu_gamma, pu_beta, pu_mean, pu_var,
                                      pv_w, pv_gamma, pv_beta, pv_mean, pv_var,
                                      conv_w, wpu, wpv, uf, vf);

    dim3 gc(128, 8);
    conv_fused<false><<<gc, 128, 0, stream>>>(uf, wpu, nullptr, nullptr, ou);
    conv_fused<true ><<<gc, 128, 0, stream>>>(vf, wpv, ou, conv_b, out);
}